// Round 9
// baseline (284.866 us; speedup 1.0000x reference)
//
#include <hip/hip_runtime.h>

#define BB 2
#define S 2048
#define H 16
#define DH 64
#define DIM 1024
#define WIN 512

#define OUT_PK 0
#define OUT_QP 134217728
#define OUT_RQ 268435456
#define OUT_RK 268959744

#define WS_BF_BASE 263168          // float index where bf16 region starts

typedef short bf16x8 __attribute__((ext_vector_type(8)));
typedef float f32x4 __attribute__((ext_vector_type(4)));

__device__ inline short f2bf(float f) {
    union { float f; unsigned int u; } cv; cv.f = f;
    unsigned int u = cv.u + 0x7FFFu + ((cv.u >> 16) & 1u);
    return (short)(u >> 16);
}

__device__ inline float bf2f(short s) {
    union { unsigned int u; float f; } cv;
    cv.u = ((unsigned int)(unsigned short)s) << 16;
    return cv.f;
}

// bf16 dot-64 of two rows
__device__ inline float dot64(const short* __restrict__ x, const short* __restrict__ y) {
    float d = 0.f;
#pragma unroll
    for (int c = 0; c < 8; ++c) {
        bf16x8 a = *reinterpret_cast<const bf16x8*>(x + c * 8);
        bf16x8 b = *reinterpret_cast<const bf16x8*>(y + c * 8);
#pragma unroll
        for (int e = 0; e < 8; ++e) d += bf2f(a[e]) * bf2f(b[e]);
    }
    return d;
}

// Launch 1: bid<256 -> fused LN+MFMA proj block; bid>=256 -> q/k f32->bf16 convert block.
__global__ __launch_bounds__(256) void prep1(const float* __restrict__ emb,
        const float* __restrict__ lnsc, const float* __restrict__ lnbi,
        const float* __restrict__ Wq, const float* __restrict__ bq,
        const float* __restrict__ Wk, const float* __restrict__ bk,
        const float* __restrict__ q, const float* __restrict__ k,
        float* __restrict__ out, short* __restrict__ rqbf, short* __restrict__ rkbf,
        short* __restrict__ qbf, short* __restrict__ kbf) {
    __shared__ short As[64 * 72];
    __shared__ short Bs[64 * 72];
    __shared__ float smu[64];
    __shared__ float srs[64];
    int bid = blockIdx.x;
    int t = threadIdx.x;

    if (bid >= 256) {
        // ---- convert path: [b,n,h,c] f32 -> [b,h,n,c] bf16 ----
        int cb = bid - 256;            // 0..2047
        int z = cb >> 10;
        int blk = cb & 1023;
        const float* src = z ? k : q;
        short* dst = z ? kbf : qbf;
        int e0 = (blk * 256 + t) * 16;
        int c = e0 & 63, hh = (e0 >> 6) & 15, n = (e0 >> 10) & 2047, b = e0 >> 21;
        short* dbase = dst + (((size_t)(b * 16 + hh) * 2048) + n) * 64 + c;
#pragma unroll
        for (int i = 0; i < 4; ++i) {
            float4 v = *reinterpret_cast<const float4*>(src + e0 + i * 4);
            short4 o = { f2bf(v.x), f2bf(v.y), f2bf(v.z), f2bf(v.w) };
            *reinterpret_cast<short4*>(dbase + i * 4) = o;
        }
        return;
    }

    // ---- proj path ----
    const float* W    = (bid >> 7) ? Wk : Wq;
    const float* bias = (bid >> 7) ? bk : bq;
    float* o = out + ((bid >> 7) ? OUT_RK : OUT_RQ);
    short* bfo = (bid >> 7) ? rkbf : rqbf;
    int r0 = (bid & 7) * 64;
    int d0 = ((bid >> 3) & 15) * 64;

    {   // LN stats, 4 threads per row
        int rr = t >> 2, p = t & 3;
        const float4* rp = reinterpret_cast<const float4*>(emb + (r0 + rr) * DIM + p * 256);
        float s = 0.f, sq = 0.f;
#pragma unroll
        for (int i = 0; i < 64; ++i) {
            float4 v = rp[i];
            s  += v.x + v.y + v.z + v.w;
            sq += v.x * v.x + v.y * v.y + v.z * v.z + v.w * v.w;
        }
        s += __shfl_xor(s, 1); sq += __shfl_xor(sq, 1);
        s += __shfl_xor(s, 2); sq += __shfl_xor(sq, 2);
        if (p == 0) {
            float mu = s / DIM;
            float var = sq / DIM - mu * mu;
            smu[rr] = mu;
            srs[rr] = rsqrtf(var + 1e-5f);
        }
    }
    __syncthreads();

    int lane = t & 63, w = t >> 6, lr = lane & 15, lg = lane >> 4;
    int srow = t >> 2, seg = (t & 3) * 16;
    float mu = smu[srow], rs = srs[srow];

    f32x4 acc[4] = {};
    for (int c0 = 0; c0 < DIM; c0 += 64) {
        const float4* ep = reinterpret_cast<const float4*>(emb + (size_t)(r0 + srow) * DIM + c0 + seg);
        const float4* wp = reinterpret_cast<const float4*>(W + (size_t)(d0 + srow) * DIM + c0 + seg);
        short4* ad = reinterpret_cast<short4*>(&As[srow * 72 + seg]);
        short4* wd = reinterpret_cast<short4*>(&Bs[srow * 72 + seg]);
#pragma unroll
        for (int i = 0; i < 4; ++i) {
            float4 v = ep[i], wv = wp[i];
            int cb2 = c0 + seg + i * 4;
            float4 sc = *reinterpret_cast<const float4*>(lnsc + cb2);
            float4 bi = *reinterpret_cast<const float4*>(lnbi + cb2);
            short4 a4 = { f2bf((v.x - mu) * rs * sc.x + bi.x),
                          f2bf((v.y - mu) * rs * sc.y + bi.y),
                          f2bf((v.z - mu) * rs * sc.z + bi.z),
                          f2bf((v.w - mu) * rs * sc.w + bi.w) };
            short4 w4 = { f2bf(wv.x), f2bf(wv.y), f2bf(wv.z), f2bf(wv.w) };
            ad[i] = a4;
            wd[i] = w4;
        }
        __syncthreads();
#pragma unroll
        for (int kk = 0; kk < 2; ++kk) {
            bf16x8 a = *reinterpret_cast<const bf16x8*>(&As[(w * 16 + lr) * 72 + kk * 32 + lg * 8]);
#pragma unroll
            for (int cg = 0; cg < 4; ++cg) {
                bf16x8 b = *reinterpret_cast<const bf16x8*>(&Bs[(cg * 16 + lr) * 72 + kk * 32 + lg * 8]);
                acc[cg] = __builtin_amdgcn_mfma_f32_16x16x32_bf16(a, b, acc[cg], 0, 0, 0);
            }
        }
        __syncthreads();
    }
#pragma unroll
    for (int cg = 0; cg < 4; ++cg) {
        int col = d0 + cg * 16 + lr;
        float bv = bias[col];
        int hh = col >> 6, cc = col & 63;
#pragma unroll
        for (int reg = 0; reg < 4; ++reg) {
            int rr = r0 + w * 16 + lg * 4 + reg;
            float val = acc[cg][reg] + bv;
            o[(size_t)rr * DIM + col] = val;
            bfo[((size_t)(hh * 512) + rr) * 64 + cc] = f2bf(val);
        }
    }
}

// Unified output kernel. Grid 29824 = 64 panels x 466 blocks (214 flat chunks + 252 band),
// XCD-swizzled so each XCD owns exactly 8 (PK,bh) panels; flat/band ~1:1 interleave in panel.
__global__ __launch_bounds__(256) void outk(const short* __restrict__ qbf,
        const short* __restrict__ kbf, const short* __restrict__ rqbf,
        const short* __restrict__ rkbf, float* __restrict__ out) {
    __shared__ short Yt[64 * 132];
    float* c_sm = reinterpret_cast<float*>(Yt);

    int bid = blockIdx.x;
    int wid = (bid & 7) * 3728 + (bid >> 3);   // 29824 = 8*3728, bijective
    int panel = wid / 466, o = wid % 466;
    int PK = panel >> 5, bh = panel & 31, h = bh & 15;
    int t = threadIdx.x;
    float* obase = out + (PK ? OUT_PK : OUT_QP) + (size_t)bh * S * S;

    int isflat, f = 0, bb = 0;
    if (o < 428) { if (!(o & 1)) { isflat = 1; f = o >> 1; } else { isflat = 0; bb = o >> 1; } }
    else         { isflat = 0; bb = 214 + (o - 428); }

    if (isflat) {
        // ---- flat chunk block: 64 rows x up to 256 cols, 1KB-contiguous wave stores ----
        int nt, j0, width, left;
        if (f < 78) {           // left region (rel = 0)
            left = 1;
            int rem = f;
            nt = 9;
            for (; nt <= 31; ++nt) { int c = (nt - 8 + 3) >> 2; if (rem < c) break; rem -= c; }
            j0 = rem * 256;
            width = (nt - 8) * 64 - j0; if (width > 256) width = 256;
        } else {                // right region (rel = 511)
            left = 0;
            int rem = f - 78;
            nt = 0;
            for (; nt <= 30; ++nt) { int c = (31 - nt + 3) >> 2; if (rem < c) break; rem -= c; }
            j0 = (nt + 1) * 64 + rem * 256;
            width = 2048 - j0; if (width > 256) width = 256;
        }
        int n0 = nt * 64;
        int trow_off = left ? 0 : 511 * 64;

        if (PK) {
            // value varies along j: c[j] = k[b,j,h] . rq[rel,h]
            const short* trow = rqbf + (size_t)h * 512 * 64 + trow_off;
            if (t < width) {
                const short* xr = kbf + ((size_t)bh * 2048 + j0 + t) * 64;
                c_sm[t] = dot64(xr, trow);
            }
            __syncthreads();
            int w = t >> 6, lane = t & 63;
            f32x4 cvv = {0.f, 0.f, 0.f, 0.f};
            if (lane * 4 < width) cvv = *reinterpret_cast<const f32x4*>(&c_sm[lane * 4]);
#pragma unroll
            for (int i = 0; i < 16; ++i) {
                int n = n0 + w * 16 + i;
                if (lane * 4 < width)
                    __builtin_nontemporal_store(cvv,
                        reinterpret_cast<f32x4*>(obase + (size_t)n * S + j0 + lane * 4));
            }
        } else {
            // value varies along n: c[n] = q[b,n,h] . rk[rel,h]
            const short* trow = rkbf + (size_t)h * 512 * 64 + trow_off;
            if (t < 64) {
                const short* xr = qbf + ((size_t)bh * 2048 + n0 + t) * 64;
                c_sm[t] = dot64(xr, trow);
            }
            __syncthreads();
            int w = t >> 6, lane = t & 63;
#pragma unroll
            for (int i = 0; i < 16; ++i) {
                int row = w * 16 + i;
                float vs = c_sm[row];
                f32x4 v = { vs, vs, vs, vs };
                if (lane * 4 < width)
                    __builtin_nontemporal_store(v,
                        reinterpret_cast<f32x4*>(obase + (size_t)(n0 + row) * S + j0 + lane * 4));
            }
        }
        return;
    }

    // ---- band tile (identical to R8) ----
    int r = bb, nt, jt;
    if (r < 45) {
        nt = 0;
        while ((nt + 1) * (nt + 2) / 2 <= r) ++nt;
        jt = r - nt * (nt + 1) / 2;
    } else {
        int r2 = r - 45;
        nt = 9 + r2 / 9;
        jt = nt - 8 + r2 % 9;
    }
    int n0 = nt * 64, j0 = jt * 64;
    int rlo = 511 + j0 - (n0 + 63); rlo = rlo < 0 ? 0 : rlo;

    const short* xb = (PK ? kbf : qbf) + ((size_t)bh * 2048 + (PK ? j0 : n0)) * 64;
    const short* tbase = (PK ? rqbf : rkbf) + (size_t)h * 512 * 64;

    int lane = t & 63, w = t >> 6, lr = lane & 15, lg = lane >> 4;
    // Same (lr, lg) convention for A and B => HW k-permutation cancels (verified R2-R8).
    const short* arow = xb + (w * 16 + lr) * 64 + lg * 8;
    bf16x8 a0 = *reinterpret_cast<const bf16x8*>(arow);
    bf16x8 a1 = *reinterpret_cast<const bf16x8*>(arow + 32);

    bf16x8 b0s[8], b1s[8];
#pragma unroll
    for (int s = 0; s < 8; ++s) {
        int trow = rlo + s * 16 + lr;
        trow = trow > 511 ? 511 : trow;   // in-bounds; g>=nT never gathered
        const short* brow = tbase + trow * 64 + lg * 8;
        b0s[s] = *reinterpret_cast<const bf16x8*>(brow);
        b1s[s] = *reinterpret_cast<const bf16x8*>(brow + 32);
    }
#pragma unroll
    for (int s = 0; s < 8; ++s) {
        f32x4 acc = {0.f, 0.f, 0.f, 0.f};
        acc = __builtin_amdgcn_mfma_f32_16x16x32_bf16(a0, b0s[s], acc, 0, 0, 0);
        acc = __builtin_amdgcn_mfma_f32_16x16x32_bf16(a1, b1s[s], acc, 0, 0, 0);
        // lane's acc[reg] = Y[m = w*16+lg*4+reg, g = s*16+lr]
#pragma unroll
        for (int reg = 0; reg < 4; ++reg)
            Yt[(w * 16 + lg * 4 + reg) * 132 + s * 16 + lr] = f2bf(acc[reg]);
    }
    __syncthreads();

    int tx = t & 15, ty = t >> 4;
#pragma unroll
    for (int i = 0; i < 4; ++i) {
        int rowi = ty + i * 16;
        int n = n0 + rowi;
        float vv[4];
#pragma unroll
        for (int jj = 0; jj < 4; ++jj) {
            int j = j0 + tx * 4 + jj;
            int rel = 511 + j - n;
            rel = rel < 0 ? 0 : (rel > 511 ? 511 : rel);
            int g = rel - rlo;
            int m = PK ? (tx * 4 + jj) : rowi;
            vv[jj] = bf2f(Yt[m * 132 + g]);
        }
        f32x4 v = { vv[0], vv[1], vv[2], vv[3] };
        __builtin_nontemporal_store(v,
            reinterpret_cast<f32x4*>(obase + (size_t)n * S + j0 + tx * 4));
    }
}

extern "C" void kernel_launch(void* const* d_in, const int* in_sizes, int n_in,
                              void* d_out, int out_size, void* d_ws, size_t ws_size,
                              hipStream_t stream) {
    const float* q    = (const float*)d_in[0];
    const float* k    = (const float*)d_in[1];
    const float* emb  = (const float*)d_in[2];
    const float* lnsc = (const float*)d_in[3];
    const float* lnbi = (const float*)d_in[4];
    const float* Wq   = (const float*)d_in[5];
    const float* bq   = (const float*)d_in[6];
    const float* Wk   = (const float*)d_in[7];
    const float* bk   = (const float*)d_in[8];
    float* out = (float*)d_out;
    float* ws  = (float*)d_ws;

    short* qbf  = (short*)(ws + WS_BF_BASE);
    short* kbf  = qbf + (size_t)4194304;
    short* rqbf = kbf + (size_t)4194304;
    short* rkbf = rqbf + (size_t)524288;

    prep1<<<dim3(2304), dim3(256), 0, stream>>>(emb, lnsc, lnbi, Wq, bq, Wk, bk,
                                                q, k, out, rqbf, rkbf, qbf, kbf);
    outk<<<dim3(29824), dim3(256), 0, stream>>>(qbf, kbf, rqbf, rkbf, out);
}

// Round 10
// 233.489 us; speedup vs baseline: 1.2200x; 1.2200x over previous
//
#include <hip/hip_runtime.h>

#define BB 2
#define S 2048
#define H 16
#define DH 64
#define DIM 1024
#define WIN 512

#define OUT_PK 0
#define OUT_QP 134217728
#define OUT_RQ 268435456
#define OUT_RK 268959744

// ws float offsets
#define WS_C0Q   1024
#define WS_C511Q (1024 + 65536)
#define WS_C0K   (1024 + 2*65536)
#define WS_C511K (1024 + 3*65536)
#define WS_BF_BASE 263168          // float index where bf16 region starts

typedef short bf16x8 __attribute__((ext_vector_type(8)));
typedef float f32x4 __attribute__((ext_vector_type(4)));

__device__ inline short f2bf(float f) {
    union { float f; unsigned int u; } cv; cv.f = f;
    unsigned int u = cv.u + 0x7FFFu + ((cv.u >> 16) & 1u);
    return (short)(u >> 16);
}

__device__ inline float bf2f(short s) {
    union { unsigned int u; float f; } cv;
    cv.u = ((unsigned int)(unsigned short)s) << 16;
    return cv.f;
}

// Launch 1: bid<256 -> fused LN+MFMA proj block; bid>=256 -> q/k f32->bf16 convert block.
// proj bid layout: z*128 + d0hi*64 + r0*8 + d0lo, so the 8 r0-blocks of one W-panel
// share bid%8 -> same XCD (round-robin dispatch) -> W panel L2-resident.
__global__ __launch_bounds__(256) void prep1(const float* __restrict__ emb,
        const float* __restrict__ lnsc, const float* __restrict__ lnbi,
        const float* __restrict__ Wq, const float* __restrict__ bq,
        const float* __restrict__ Wk, const float* __restrict__ bk,
        const float* __restrict__ q, const float* __restrict__ k,
        float* __restrict__ out, short* __restrict__ rqbf, short* __restrict__ rkbf,
        short* __restrict__ qbf, short* __restrict__ kbf) {
    __shared__ short As[64 * 72];
    __shared__ short Bs[64 * 72];
    __shared__ float smu[64];
    __shared__ float srs[64];
    int bid = blockIdx.x;
    int t = threadIdx.x;

    if (bid >= 256) {
        // ---- convert path: [b,n,h,c] f32 -> [b,h,n,c] bf16 ----
        int cb = bid - 256;            // 0..2047
        int z = cb >> 10;
        int blk = cb & 1023;
        const float* src = z ? k : q;
        short* dst = z ? kbf : qbf;
        int e0 = (blk * 256 + t) * 16;
        int c = e0 & 63, hh = (e0 >> 6) & 15, n = (e0 >> 10) & 2047, b = e0 >> 21;
        short* dbase = dst + (((size_t)(b * 16 + hh) * 2048) + n) * 64 + c;
#pragma unroll
        for (int i = 0; i < 4; ++i) {
            float4 v = *reinterpret_cast<const float4*>(src + e0 + i * 4);
            short4 o = { f2bf(v.x), f2bf(v.y), f2bf(v.z), f2bf(v.w) };
            *reinterpret_cast<short4*>(dbase + i * 4) = o;
        }
        return;
    }

    // ---- proj path ----
    int z = bid >> 7;
    int d0i = ((bid >> 6) & 1) * 8 + (bid & 7);
    int r0i = (bid >> 3) & 7;
    const float* W    = z ? Wk : Wq;
    const float* bias = z ? bk : bq;
    float* o = out + (z ? OUT_RK : OUT_RQ);
    short* bfo = z ? rkbf : rqbf;
    int r0 = r0i * 64;
    int d0 = d0i * 64;

    {   // LN stats, 4 threads per row
        int rr = t >> 2, p = t & 3;
        const float4* rp = reinterpret_cast<const float4*>(emb + (r0 + rr) * DIM + p * 256);
        float s = 0.f, sq = 0.f;
#pragma unroll
        for (int i = 0; i < 64; ++i) {
            float4 v = rp[i];
            s  += v.x + v.y + v.z + v.w;
            sq += v.x * v.x + v.y * v.y + v.z * v.z + v.w * v.w;
        }
        s += __shfl_xor(s, 1); sq += __shfl_xor(sq, 1);
        s += __shfl_xor(s, 2); sq += __shfl_xor(sq, 2);
        if (p == 0) {
            float mu = s / DIM;
            float var = sq / DIM - mu * mu;
            smu[rr] = mu;
            srs[rr] = rsqrtf(var + 1e-5f);
        }
    }
    __syncthreads();

    int lane = t & 63, w = t >> 6, lr = lane & 15, lg = lane >> 4;
    int srow = t >> 2, seg = (t & 3) * 16;
    float mu = smu[srow], rs = srs[srow];

    f32x4 acc[4] = {};
    for (int c0 = 0; c0 < DIM; c0 += 64) {
        const float4* ep = reinterpret_cast<const float4*>(emb + (size_t)(r0 + srow) * DIM + c0 + seg);
        const float4* wp = reinterpret_cast<const float4*>(W + (size_t)(d0 + srow) * DIM + c0 + seg);
        short4* ad = reinterpret_cast<short4*>(&As[srow * 72 + seg]);
        short4* wd = reinterpret_cast<short4*>(&Bs[srow * 72 + seg]);
#pragma unroll
        for (int i = 0; i < 4; ++i) {
            float4 v = ep[i], wv = wp[i];
            int cb2 = c0 + seg + i * 4;
            float4 sc = *reinterpret_cast<const float4*>(lnsc + cb2);
            float4 bi = *reinterpret_cast<const float4*>(lnbi + cb2);
            short4 a4 = { f2bf((v.x - mu) * rs * sc.x + bi.x),
                          f2bf((v.y - mu) * rs * sc.y + bi.y),
                          f2bf((v.z - mu) * rs * sc.z + bi.z),
                          f2bf((v.w - mu) * rs * sc.w + bi.w) };
            short4 w4 = { f2bf(wv.x), f2bf(wv.y), f2bf(wv.z), f2bf(wv.w) };
            ad[i] = a4;
            wd[i] = w4;
        }
        __syncthreads();
#pragma unroll
        for (int kk = 0; kk < 2; ++kk) {
            bf16x8 a = *reinterpret_cast<const bf16x8*>(&As[(w * 16 + lr) * 72 + kk * 32 + lg * 8]);
#pragma unroll
            for (int cg = 0; cg < 4; ++cg) {
                bf16x8 b = *reinterpret_cast<const bf16x8*>(&Bs[(cg * 16 + lr) * 72 + kk * 32 + lg * 8]);
                acc[cg] = __builtin_amdgcn_mfma_f32_16x16x32_bf16(a, b, acc[cg], 0, 0, 0);
            }
        }
        __syncthreads();
    }
#pragma unroll
    for (int cg = 0; cg < 4; ++cg) {
        int col = d0 + cg * 16 + lr;
        float bv = bias[col];
        int hh = col >> 6, cc = col & 63;
#pragma unroll
        for (int reg = 0; reg < 4; ++reg) {
            int rr = r0 + w * 16 + lg * 4 + reg;
            float val = acc[cg][reg] + bv;
            o[(size_t)rr * DIM + col] = val;
            bfo[((size_t)(hh * 512) + rr) * 64 + cc] = f2bf(val);
        }
    }
}

// cvec: c0/c511 dot tables from bf16 copies. z=0: q . rk[0/511] -> C0Q/C511Q; z=1: k . rq[0/511]
__global__ __launch_bounds__(256) void cvec(const short* __restrict__ qbf,
        const short* __restrict__ kbf, const short* __restrict__ rqbf,
        const short* __restrict__ rkbf, float* __restrict__ ws) {
    int cid = blockIdx.x;           // 0..2047
    int z = cid >> 10;
    int rem = cid & 1023;
    int bh = rem >> 5, rb = rem & 31;
    int t = threadIdx.x;
    int rr = t >> 2, p = t & 3;
    int n = rb * 64 + rr;
    int h = bh & 15;
    const short* X = (z ? kbf : qbf) + ((size_t)bh * 2048 + n) * 64 + p * 16;
    const short* T = (z ? rqbf : rkbf) + (size_t)h * 512 * 64 + p * 16;
    bf16x8 x0 = *reinterpret_cast<const bf16x8*>(X);
    bf16x8 x1 = *reinterpret_cast<const bf16x8*>(X + 8);
    bf16x8 a0 = *reinterpret_cast<const bf16x8*>(T);
    bf16x8 a1 = *reinterpret_cast<const bf16x8*>(T + 8);
    bf16x8 c0 = *reinterpret_cast<const bf16x8*>(T + 511 * 64);
    bf16x8 c1 = *reinterpret_cast<const bf16x8*>(T + 511 * 64 + 8);
    float d0 = 0.f, d1 = 0.f;
#pragma unroll
    for (int e = 0; e < 8; ++e) {
        float xa = bf2f(x0[e]), xb = bf2f(x1[e]);
        d0 += xa * bf2f(a0[e]) + xb * bf2f(a1[e]);
        d1 += xa * bf2f(c0[e]) + xb * bf2f(c1[e]);
    }
    d0 += __shfl_xor(d0, 1); d0 += __shfl_xor(d0, 2);
    d1 += __shfl_xor(d1, 1); d1 += __shfl_xor(d1, 2);
    if (p == 0) {
        int o = bh * S + n;
        if (!z) { ws[WS_C0Q + o] = d0; ws[WS_C511Q + o] = d1; }
        else    { ws[WS_C0K + o] = d0; ws[WS_C511K + o] = d1; }
    }
}

// Unified output kernel, 1D grid 65536 with bijective XCD swizzle.  (R8-proven ordering)
// work id wg = ((PK*32)+bh)*1024 + nt*32 + jt
__global__ __launch_bounds__(256) void outk(const short* __restrict__ qbf,
        const short* __restrict__ kbf, const short* __restrict__ rqbf,
        const short* __restrict__ rkbf, const float* __restrict__ ws,
        float* __restrict__ out) {
    __shared__ short Yt[128 * 68];   // [g][m], b64 accumulator stores

    int bid = blockIdx.x;
    int wg = (bid & 7) * 8192 + (bid >> 3);   // 65536 % 8 == 0 -> bijective
    int PK = wg >> 15;
    int bh = (wg >> 10) & 31; int h = bh & 15;
    int nt = (wg >> 5) & 31, jt = wg & 31;
    int n0 = nt * 64, j0 = jt * 64;
    int jlo = nt > 8 ? nt - 8 : 0;
    int t = threadIdx.x;
    float* obase = out + (PK ? OUT_PK : OUT_QP) + (size_t)bh * S * S;

    if (jt < jlo || jt > nt) {
        // Flat tile: rel=0 (left) or rel=511 (right)
        int left = jt < jlo;
        const float* cv = ws + (PK ? (left ? WS_C0K : WS_C511K)
                                   : (left ? WS_C0Q : WS_C511Q)) + bh * S;
        int col4 = t & 15, r0w = t >> 4;
        if (PK) {
            f32x4 v = *reinterpret_cast<const f32x4*>(cv + j0 + col4 * 4);
#pragma unroll
            for (int i = 0; i < 4; ++i) {
                int n = n0 + r0w + i * 16;
                __builtin_nontemporal_store(v,
                    reinterpret_cast<f32x4*>(obase + (size_t)n * S + j0 + col4 * 4));
            }
        } else {
#pragma unroll
            for (int i = 0; i < 4; ++i) {
                int n = n0 + r0w + i * 16;
                float vs = cv[n];
                f32x4 v = { vs, vs, vs, vs };
                __builtin_nontemporal_store(v,
                    reinterpret_cast<f32x4*>(obase + (size_t)n * S + j0 + col4 * 4));
            }
        }
        return;
    }

    // Band tile
    int rlo = 511 + j0 - (n0 + 63); rlo = rlo < 0 ? 0 : rlo;

    const short* xb = (PK ? kbf : qbf) + ((size_t)bh * 2048 + (PK ? j0 : n0)) * 64;
    const short* tbase = (PK ? rqbf : rkbf) + (size_t)h * 512 * 64;

    int lane = t & 63, w = t >> 6, lr = lane & 15, lg = lane >> 4;
    // Same (lr, lg) convention for A and B => HW k-permutation cancels (verified R2-R9).
    const short* arow = xb + (w * 16 + lr) * 64 + lg * 8;
    bf16x8 a0 = *reinterpret_cast<const bf16x8*>(arow);
    bf16x8 a1 = *reinterpret_cast<const bf16x8*>(arow + 32);

    // Front all 16 B-loads so their latency overlaps (static indices -> registers).
    bf16x8 b0s[8], b1s[8];
#pragma unroll
    for (int s = 0; s < 8; ++s) {
        int trow = rlo + s * 16 + lr;
        trow = trow > 511 ? 511 : trow;   // in-bounds; g>=nT never gathered
        const short* brow = tbase + trow * 64 + lg * 8;
        b0s[s] = *reinterpret_cast<const bf16x8*>(brow);
        b1s[s] = *reinterpret_cast<const bf16x8*>(brow + 32);
    }
#pragma unroll
    for (int s = 0; s < 8; ++s) {
        f32x4 acc = {0.f, 0.f, 0.f, 0.f};
        acc = __builtin_amdgcn_mfma_f32_16x16x32_bf16(a0, b0s[s], acc, 0, 0, 0);
        acc = __builtin_amdgcn_mfma_f32_16x16x32_bf16(a1, b1s[s], acc, 0, 0, 0);
        // lane's acc[reg] = Y[m = w*16+lg*4+reg, g = s*16+lr]; regs = consecutive m
        // -> single ds_write_b64 into Yt[g][m0..m0+3]
        short4 pk4 = { f2bf(acc[0]), f2bf(acc[1]), f2bf(acc[2]), f2bf(acc[3]) };
        *reinterpret_cast<short4*>(&Yt[(s * 16 + lr) * 68 + w * 16 + lg * 4]) = pk4;
    }
    __syncthreads();

    int tx = t & 15, ty = t >> 4;
#pragma unroll
    for (int i = 0; i < 4; ++i) {
        int rowi = ty + i * 16;
        int n = n0 + rowi;
        float vv[4];
#pragma unroll
        for (int jj = 0; jj < 4; ++jj) {
            int j = j0 + tx * 4 + jj;
            int rel = 511 + j - n;
            rel = rel < 0 ? 0 : (rel > 511 ? 511 : rel);
            int g = rel - rlo;
            int m = PK ? (tx * 4 + jj) : rowi;
            vv[jj] = bf2f(Yt[g * 68 + m]);
        }
        f32x4 v = { vv[0], vv[1], vv[2], vv[3] };
        __builtin_nontemporal_store(v,
            reinterpret_cast<f32x4*>(obase + (size_t)n * S + j0 + tx * 4));
    }
}

extern "C" void kernel_launch(void* const* d_in, const int* in_sizes, int n_in,
                              void* d_out, int out_size, void* d_ws, size_t ws_size,
                              hipStream_t stream) {
    const float* q    = (const float*)d_in[0];
    const float* k    = (const float*)d_in[1];
    const float* emb  = (const float*)d_in[2];
    const float* lnsc = (const float*)d_in[3];
    const float* lnbi = (const float*)d_in[4];
    const float* Wq   = (const float*)d_in[5];
    const float* bq   = (const float*)d_in[6];
    const float* Wk   = (const float*)d_in[7];
    const float* bk   = (const float*)d_in[8];
    float* out = (float*)d_out;
    float* ws  = (float*)d_ws;

    short* qbf  = (short*)(ws + WS_BF_BASE);
    short* kbf  = qbf + (size_t)4194304;
    short* rqbf = kbf + (size_t)4194304;
    short* rkbf = rqbf + (size_t)524288;

    prep1<<<dim3(2304), dim3(256), 0, stream>>>(emb, lnsc, lnbi, Wq, bq, Wk, bk,
                                                q, k, out, rqbf, rkbf, qbf, kbf);
    cvec<<<dim3(2048), dim3(256), 0, stream>>>(qbf, kbf, rqbf, rkbf, ws);
    outk<<<dim3(65536), dim3(256), 0, stream>>>(qbf, kbf, rqbf, rkbf, ws, out);
}

// Round 12
// 228.992 us; speedup vs baseline: 1.2440x; 1.0196x over previous
//
#include <hip/hip_runtime.h>

#define BB 2
#define S 2048
#define H 16
#define DH 64
#define DIM 1024
#define WIN 512

#define OUT_PK 0
#define OUT_QP 134217728
#define OUT_RQ 268435456
#define OUT_RK 268959744

// ws float offsets
#define WS_C0Q   1024
#define WS_C511Q (1024 + 65536)
#define WS_C0K   (1024 + 2*65536)
#define WS_C511K (1024 + 3*65536)
#define WS_BF_BASE 263168          // float index where bf16 region starts

typedef short bf16x8 __attribute__((ext_vector_type(8)));
typedef float f32x4 __attribute__((ext_vector_type(4)));

__device__ inline short f2bf(float f) {
    union { float f; unsigned int u; } cv; cv.f = f;
    unsigned int u = cv.u + 0x7FFFu + ((cv.u >> 16) & 1u);
    return (short)(u >> 16);
}

__device__ inline float bf2f(short s) {
    union { unsigned int u; float f; } cv;
    cv.u = ((unsigned int)(unsigned short)s) << 16;
    return cv.f;
}

// Launch 1: bid<256 -> fused LN+MFMA proj block; bid>=256 -> q/k f32->bf16 convert block.
__global__ __launch_bounds__(256) void prep1(const float* __restrict__ emb,
        const float* __restrict__ lnsc, const float* __restrict__ lnbi,
        const float* __restrict__ Wq, const float* __restrict__ bq,
        const float* __restrict__ Wk, const float* __restrict__ bk,
        const float* __restrict__ q, const float* __restrict__ k,
        float* __restrict__ out, short* __restrict__ rqbf, short* __restrict__ rkbf,
        short* __restrict__ qbf, short* __restrict__ kbf) {
    __shared__ short As[64 * 72];
    __shared__ short Bs[64 * 72];
    __shared__ float smu[64];
    __shared__ float srs[64];
    int bid = blockIdx.x;
    int t = threadIdx.x;

    if (bid >= 256) {
        // ---- convert path: [b,n,h,c] f32 -> [b,h,n,c] bf16 ----
        int cb = bid - 256;            // 0..2047
        int z = cb >> 10;
        int blk = cb & 1023;
        const float* src = z ? k : q;
        short* dst = z ? kbf : qbf;
        int e0 = (blk * 256 + t) * 16;
        int c = e0 & 63, hh = (e0 >> 6) & 15, n = (e0 >> 10) & 2047, b = e0 >> 21;
        short* dbase = dst + (((size_t)(b * 16 + hh) * 2048) + n) * 64 + c;
#pragma unroll
        for (int i = 0; i < 4; ++i) {
            float4 v = *reinterpret_cast<const float4*>(src + e0 + i * 4);
            short4 o = { f2bf(v.x), f2bf(v.y), f2bf(v.z), f2bf(v.w) };
            *reinterpret_cast<short4*>(dbase + i * 4) = o;
        }
        return;
    }

    // ---- proj path ----
    int z = bid >> 7;
    int d0i = ((bid >> 6) & 1) * 8 + (bid & 7);
    int r0i = (bid >> 3) & 7;
    const float* W    = z ? Wk : Wq;
    const float* bias = z ? bk : bq;
    float* o = out + (z ? OUT_RK : OUT_RQ);
    short* bfo = z ? rkbf : rqbf;
    int r0 = r0i * 64;
    int d0 = d0i * 64;

    {   // LN stats, 4 threads per row
        int rr = t >> 2, p = t & 3;
        const float4* rp = reinterpret_cast<const float4*>(emb + (r0 + rr) * DIM + p * 256);
        float s = 0.f, sq = 0.f;
#pragma unroll
        for (int i = 0; i < 64; ++i) {
            float4 v = rp[i];
            s  += v.x + v.y + v.z + v.w;
            sq += v.x * v.x + v.y * v.y + v.z * v.z + v.w * v.w;
        }
        s += __shfl_xor(s, 1); sq += __shfl_xor(sq, 1);
        s += __shfl_xor(s, 2); sq += __shfl_xor(sq, 2);
        if (p == 0) {
            float mu = s / DIM;
            float var = sq / DIM - mu * mu;
            smu[rr] = mu;
            srs[rr] = rsqrtf(var + 1e-5f);
        }
    }
    __syncthreads();

    int lane = t & 63, w = t >> 6, lr = lane & 15, lg = lane >> 4;
    int srow = t >> 2, seg = (t & 3) * 16;
    float mu = smu[srow], rs = srs[srow];

    f32x4 acc[4] = {};
    for (int c0 = 0; c0 < DIM; c0 += 64) {
        const float4* ep = reinterpret_cast<const float4*>(emb + (size_t)(r0 + srow) * DIM + c0 + seg);
        const float4* wp = reinterpret_cast<const float4*>(W + (size_t)(d0 + srow) * DIM + c0 + seg);
        short4* ad = reinterpret_cast<short4*>(&As[srow * 72 + seg]);
        short4* wd = reinterpret_cast<short4*>(&Bs[srow * 72 + seg]);
#pragma unroll
        for (int i = 0; i < 4; ++i) {
            float4 v = ep[i], wv = wp[i];
            int cb2 = c0 + seg + i * 4;
            float4 sc = *reinterpret_cast<const float4*>(lnsc + cb2);
            float4 bi = *reinterpret_cast<const float4*>(lnbi + cb2);
            short4 a4 = { f2bf((v.x - mu) * rs * sc.x + bi.x),
                          f2bf((v.y - mu) * rs * sc.y + bi.y),
                          f2bf((v.z - mu) * rs * sc.z + bi.z),
                          f2bf((v.w - mu) * rs * sc.w + bi.w) };
            short4 w4 = { f2bf(wv.x), f2bf(wv.y), f2bf(wv.z), f2bf(wv.w) };
            ad[i] = a4;
            wd[i] = w4;
        }
        __syncthreads();
#pragma unroll
        for (int kk = 0; kk < 2; ++kk) {
            bf16x8 a = *reinterpret_cast<const bf16x8*>(&As[(w * 16 + lr) * 72 + kk * 32 + lg * 8]);
#pragma unroll
            for (int cg = 0; cg < 4; ++cg) {
                bf16x8 b = *reinterpret_cast<const bf16x8*>(&Bs[(cg * 16 + lr) * 72 + kk * 32 + lg * 8]);
                acc[cg] = __builtin_amdgcn_mfma_f32_16x16x32_bf16(a, b, acc[cg], 0, 0, 0);
            }
        }
        __syncthreads();
    }
#pragma unroll
    for (int cg = 0; cg < 4; ++cg) {
        int col = d0 + cg * 16 + lr;
        float bv = bias[col];
        int hh = col >> 6, cc = col & 63;
#pragma unroll
        for (int reg = 0; reg < 4; ++reg) {
            int rr = r0 + w * 16 + lg * 4 + reg;
            float val = acc[cg][reg] + bv;
            o[(size_t)rr * DIM + col] = val;
            bfo[((size_t)(hh * 512) + rr) * 64 + cc] = f2bf(val);
        }
    }
}

// cvec: c0/c511 dot tables from bf16 copies. z=0: q . rk[0/511] -> C0Q/C511Q; z=1: k . rq[0/511]
__global__ __launch_bounds__(256) void cvec(const short* __restrict__ qbf,
        const short* __restrict__ kbf, const short* __restrict__ rqbf,
        const short* __restrict__ rkbf, float* __restrict__ ws) {
    int cid = blockIdx.x;           // 0..2047
    int z = cid >> 10;
    int rem = cid & 1023;
    int bh = rem >> 5, rb = rem & 31;
    int t = threadIdx.x;
    int rr = t >> 2, p = t & 3;
    int n = rb * 64 + rr;
    int h = bh & 15;
    const short* X = (z ? kbf : qbf) + ((size_t)bh * 2048 + n) * 64 + p * 16;
    const short* T = (z ? rqbf : rkbf) + (size_t)h * 512 * 64 + p * 16;
    bf16x8 x0 = *reinterpret_cast<const bf16x8*>(X);
    bf16x8 x1 = *reinterpret_cast<const bf16x8*>(X + 8);
    bf16x8 a0 = *reinterpret_cast<const bf16x8*>(T);
    bf16x8 a1 = *reinterpret_cast<const bf16x8*>(T + 8);
    bf16x8 c0 = *reinterpret_cast<const bf16x8*>(T + 511 * 64);
    bf16x8 c1 = *reinterpret_cast<const bf16x8*>(T + 511 * 64 + 8);
    float d0 = 0.f, d1 = 0.f;
#pragma unroll
    for (int e = 0; e < 8; ++e) {
        float xa = bf2f(x0[e]), xb = bf2f(x1[e]);
        d0 += xa * bf2f(a0[e]) + xb * bf2f(a1[e]);
        d1 += xa * bf2f(c0[e]) + xb * bf2f(c1[e]);
    }
    d0 += __shfl_xor(d0, 1); d0 += __shfl_xor(d0, 2);
    d1 += __shfl_xor(d1, 1); d1 += __shfl_xor(d1, 2);
    if (p == 0) {
        int o = bh * S + n;
        if (!z) { ws[WS_C0Q + o] = d0; ws[WS_C511Q + o] = d1; }
        else    { ws[WS_C0K + o] = d0; ws[WS_C511K + o] = d1; }
    }
}

// Unified output kernel. Per panel: nt-major sweep (R8 ordering), flat runs merged into
// 64x256 superblocks (1KB-contiguous wave stores). 466 blocks/panel, 64 panels = 29824.
__global__ __launch_bounds__(256) void outk(const short* __restrict__ qbf,
        const short* __restrict__ kbf, const short* __restrict__ rqbf,
        const short* __restrict__ rkbf, const float* __restrict__ ws,
        float* __restrict__ out) {
    __shared__ short Yt[128 * 68];   // [g][m] (band path only)

    int bid = blockIdx.x;
    int wid = (bid & 7) * 3728 + (bid >> 3);   // 29824 = 8*3728, bijective
    int panel = wid / 466, o = wid % 466;
    int PK = panel >> 5, bh = panel & 31, h = bh & 15;
    int t = threadIdx.x;
    float* obase = out + (PK ? OUT_PK : OUT_QP) + (size_t)bh * S * S;

    // locate within panel: for each nt, [nL left-superblocks][nB band][nR right-superblocks]
    int nt = 0, rem = o, nL = 0, nB = 0, jlo = 0;
    for (; nt < 32; ++nt) {
        jlo = nt > 8 ? nt - 8 : 0;
        nL = (jlo + 3) >> 2;
        nB = nt - jlo + 1;
        int nR = (34 - nt) >> 2;      // ceil((31-nt)/4)
        int tot = nL + nB + nR;
        if (rem < tot) break;
        rem -= tot;
    }
    int n0 = nt * 64;

    if (rem < nL || rem >= nL + nB) {
        // ---- flat superblock: 64 rows x W cols (W<=256), 1KB-contiguous wave stores ----
        int left, j0, W;
        if (rem < nL) { left = 1; j0 = rem * 256; W = jlo * 64 - j0; }
        else          { left = 0; int rr = rem - nL - nB; j0 = (nt + 1) * 64 + rr * 256; W = 2048 - j0; }
        if (W > 256) W = 256;
        const float* cv = ws + (PK ? (left ? WS_C0K : WS_C511K)
                                   : (left ? WS_C0Q : WS_C511Q)) + bh * S;
        int w = t >> 6, lane = t & 63;
        int active = lane * 4 < W;
        if (PK) {
            f32x4 cvv = {0.f, 0.f, 0.f, 0.f};
            if (active) cvv = *reinterpret_cast<const f32x4*>(cv + j0 + lane * 4);
#pragma unroll
            for (int i = 0; i < 16; ++i) {
                int n = n0 + w * 16 + i;
                if (active)
                    __builtin_nontemporal_store(cvv,
                        reinterpret_cast<f32x4*>(obase + (size_t)n * S + j0 + lane * 4));
            }
        } else {
            float vs[16];
#pragma unroll
            for (int i = 0; i < 16; ++i) vs[i] = cv[n0 + w * 16 + i];
#pragma unroll
            for (int i = 0; i < 16; ++i) {
                int n = n0 + w * 16 + i;
                f32x4 v = { vs[i], vs[i], vs[i], vs[i] };
                if (active)
                    __builtin_nontemporal_store(v,
                        reinterpret_cast<f32x4*>(obase + (size_t)n * S + j0 + lane * 4));
            }
        }
        return;
    }

    // ---- band tile ----
    int jt = jlo + (rem - nL);
    int j0 = jt * 64;
    int rlo = 511 + j0 - (n0 + 63); rlo = rlo < 0 ? 0 : rlo;

    const short* xb = (PK ? kbf : qbf) + ((size_t)bh * 2048 + (PK ? j0 : n0)) * 64;
    const short* tbase = (PK ? rqbf : rkbf) + (size_t)h * 512 * 64;

    int lane = t & 63, w = t >> 6, lr = lane & 15, lg = lane >> 4;
    // Same (lr, lg) convention for A and B => HW k-permutation cancels (verified R2-R10).
    const short* arow = xb + (w * 16 + lr) * 64 + lg * 8;
    bf16x8 a0 = *reinterpret_cast<const bf16x8*>(arow);
    bf16x8 a1 = *reinterpret_cast<const bf16x8*>(arow + 32);

    bf16x8 b0s[8], b1s[8];
#pragma unroll
    for (int s = 0; s < 8; ++s) {
        int trow = rlo + s * 16 + lr;
        trow = trow > 511 ? 511 : trow;   // in-bounds; g>=nT never gathered
        const short* brow = tbase + trow * 64 + lg * 8;
        b0s[s] = *reinterpret_cast<const bf16x8*>(brow);
        b1s[s] = *reinterpret_cast<const bf16x8*>(brow + 32);
    }
#pragma unroll
    for (int s = 0; s < 8; ++s) {
        f32x4 acc = {0.f, 0.f, 0.f, 0.f};
        acc = __builtin_amdgcn_mfma_f32_16x16x32_bf16(a0, b0s[s], acc, 0, 0, 0);
        acc = __builtin_amdgcn_mfma_f32_16x16x32_bf16(a1, b1s[s], acc, 0, 0, 0);
        // lane's acc[reg] = Y[m = w*16+lg*4+reg, g = s*16+lr] -> ds_write_b64 at Yt[g][m0]
        short4 pk4 = { f2bf(acc[0]), f2bf(acc[1]), f2bf(acc[2]), f2bf(acc[3]) };
        *reinterpret_cast<short4*>(&Yt[(s * 16 + lr) * 68 + w * 16 + lg * 4]) = pk4;
    }
    __syncthreads();

    int tx = t & 15, ty = t >> 4;
#pragma unroll
    for (int i = 0; i < 4; ++i) {
        int rowi = ty + i * 16;
        int n = n0 + rowi;
        float vv[4];
#pragma unroll
        for (int jj = 0; jj < 4; ++jj) {
            int j = j0 + tx * 4 + jj;
            int rel = 511 + j - n;
            rel = rel < 0 ? 0 : (rel > 511 ? 511 : rel);
            int g = rel - rlo;
            int m = PK ? (tx * 4 + jj) : rowi;
            vv[jj] = bf2f(Yt[g * 68 + m]);
        }
        f32x4 v = { vv[0], vv[1], vv[2], vv[3] };
        __builtin_nontemporal_store(v,
            reinterpret_cast<f32x4*>(obase + (size_t)n * S + j0 + tx * 4));
    }
}

extern "C" void kernel_launch(void* const* d_in, const int* in_sizes, int n_in,
                              void* d_out, int out_size, void* d_ws, size_t ws_size,
                              hipStream_t stream) {
    const float* q    = (const float*)d_in[0];
    const float* k    = (const float*)d_in[1];
    const float* emb  = (const float*)d_in[2];
    const float* lnsc = (const float*)d_in[3];
    const float* lnbi = (const float*)d_in[4];
    const float* Wq   = (const float*)d_in[5];
    const float* bq   = (const float*)d_in[6];
    const float* Wk   = (const float*)d_in[7];
    const float* bk   = (const float*)d_in[8];
    float* out = (float*)d_out;
    float* ws  = (float*)d_ws;

    short* qbf  = (short*)(ws + WS_BF_BASE);
    short* kbf  = qbf + (size_t)4194304;
    short* rqbf = kbf + (size_t)4194304;
    short* rkbf = rqbf + (size_t)524288;

    prep1<<<dim3(2304), dim3(256), 0, stream>>>(emb, lnsc, lnbi, Wq, bq, Wk, bk,
                                                q, k, out, rqbf, rkbf, qbf, kbf);
    cvec<<<dim3(2048), dim3(256), 0, stream>>>(qbf, kbf, rqbf, rkbf, ws);
    outk<<<dim3(29824), dim3(256), 0, stream>>>(qbf, kbf, rqbf, rkbf, ws, out);
}

// Round 13
// 226.204 us; speedup vs baseline: 1.2593x; 1.0123x over previous
//
#include <hip/hip_runtime.h>

#define BB 2
#define S 2048
#define H 16
#define DH 64
#define DIM 1024
#define WIN 512

#define OUT_PK 0
#define OUT_QP 134217728
#define OUT_RQ 268435456
#define OUT_RK 268959744

// ws float offsets
#define WS_C0Q   1024
#define WS_C511Q (1024 + 65536)
#define WS_C0K   (1024 + 2*65536)
#define WS_C511K (1024 + 3*65536)
#define WS_BF_BASE 263168          // float index where bf16 region starts

typedef short bf16x8 __attribute__((ext_vector_type(8)));
typedef float f32x4 __attribute__((ext_vector_type(4)));

__device__ inline short f2bf(float f) {
    union { float f; unsigned int u; } cv; cv.f = f;
    unsigned int u = cv.u + 0x7FFFu + ((cv.u >> 16) & 1u);
    return (short)(u >> 16);
}

__device__ inline float bf2f(short s) {
    union { unsigned int u; float f; } cv;
    cv.u = ((unsigned int)(unsigned short)s) << 16;
    return cv.f;
}

// Launch 1: bid<256 -> fused LN+MFMA proj block; bid>=256 -> q/k f32->bf16 convert block.
__global__ __launch_bounds__(256) void prep1(const float* __restrict__ emb,
        const float* __restrict__ lnsc, const float* __restrict__ lnbi,
        const float* __restrict__ Wq, const float* __restrict__ bq,
        const float* __restrict__ Wk, const float* __restrict__ bk,
        const float* __restrict__ q, const float* __restrict__ k,
        float* __restrict__ out, short* __restrict__ rqbf, short* __restrict__ rkbf,
        short* __restrict__ qbf, short* __restrict__ kbf) {
    __shared__ short As[64 * 72];
    __shared__ short Bs[64 * 72];
    __shared__ float smu[64];
    __shared__ float srs[64];
    int bid = blockIdx.x;
    int t = threadIdx.x;

    if (bid >= 256) {
        // ---- convert path: [b,n,h,c] f32 -> [b,h,n,c] bf16 ----
        int cb = bid - 256;            // 0..2047
        int z = cb >> 10;
        int blk = cb & 1023;
        const float* src = z ? k : q;
        short* dst = z ? kbf : qbf;
        int e0 = (blk * 256 + t) * 16;
        int c = e0 & 63, hh = (e0 >> 6) & 15, n = (e0 >> 10) & 2047, b = e0 >> 21;
        short* dbase = dst + (((size_t)(b * 16 + hh) * 2048) + n) * 64 + c;
#pragma unroll
        for (int i = 0; i < 4; ++i) {
            float4 v = *reinterpret_cast<const float4*>(src + e0 + i * 4);
            short4 o = { f2bf(v.x), f2bf(v.y), f2bf(v.z), f2bf(v.w) };
            *reinterpret_cast<short4*>(dbase + i * 4) = o;
        }
        return;
    }

    // ---- proj path ----
    int z = bid >> 7;
    int d0i = ((bid >> 6) & 1) * 8 + (bid & 7);
    int r0i = (bid >> 3) & 7;
    const float* W    = z ? Wk : Wq;
    const float* bias = z ? bk : bq;
    float* o = out + (z ? OUT_RK : OUT_RQ);
    short* bfo = z ? rkbf : rqbf;
    int r0 = r0i * 64;
    int d0 = d0i * 64;

    {   // LN stats, 4 threads per row
        int rr = t >> 2, p = t & 3;
        const float4* rp = reinterpret_cast<const float4*>(emb + (r0 + rr) * DIM + p * 256);
        float s = 0.f, sq = 0.f;
#pragma unroll
        for (int i = 0; i < 64; ++i) {
            float4 v = rp[i];
            s  += v.x + v.y + v.z + v.w;
            sq += v.x * v.x + v.y * v.y + v.z * v.z + v.w * v.w;
        }
        s += __shfl_xor(s, 1); sq += __shfl_xor(sq, 1);
        s += __shfl_xor(s, 2); sq += __shfl_xor(sq, 2);
        if (p == 0) {
            float mu = s / DIM;
            float var = sq / DIM - mu * mu;
            smu[rr] = mu;
            srs[rr] = rsqrtf(var + 1e-5f);
        }
    }
    __syncthreads();

    int lane = t & 63, w = t >> 6, lr = lane & 15, lg = lane >> 4;
    int srow = t >> 2, seg = (t & 3) * 16;
    float mu = smu[srow], rs = srs[srow];

    f32x4 acc[4] = {};
    for (int c0 = 0; c0 < DIM; c0 += 64) {
        const float4* ep = reinterpret_cast<const float4*>(emb + (size_t)(r0 + srow) * DIM + c0 + seg);
        const float4* wp = reinterpret_cast<const float4*>(W + (size_t)(d0 + srow) * DIM + c0 + seg);
        short4* ad = reinterpret_cast<short4*>(&As[srow * 72 + seg]);
        short4* wd = reinterpret_cast<short4*>(&Bs[srow * 72 + seg]);
#pragma unroll
        for (int i = 0; i < 4; ++i) {
            float4 v = ep[i], wv = wp[i];
            int cb2 = c0 + seg + i * 4;
            float4 sc = *reinterpret_cast<const float4*>(lnsc + cb2);
            float4 bi = *reinterpret_cast<const float4*>(lnbi + cb2);
            short4 a4 = { f2bf((v.x - mu) * rs * sc.x + bi.x),
                          f2bf((v.y - mu) * rs * sc.y + bi.y),
                          f2bf((v.z - mu) * rs * sc.z + bi.z),
                          f2bf((v.w - mu) * rs * sc.w + bi.w) };
            short4 w4 = { f2bf(wv.x), f2bf(wv.y), f2bf(wv.z), f2bf(wv.w) };
            ad[i] = a4;
            wd[i] = w4;
        }
        __syncthreads();
#pragma unroll
        for (int kk = 0; kk < 2; ++kk) {
            bf16x8 a = *reinterpret_cast<const bf16x8*>(&As[(w * 16 + lr) * 72 + kk * 32 + lg * 8]);
#pragma unroll
            for (int cg = 0; cg < 4; ++cg) {
                bf16x8 b = *reinterpret_cast<const bf16x8*>(&Bs[(cg * 16 + lr) * 72 + kk * 32 + lg * 8]);
                acc[cg] = __builtin_amdgcn_mfma_f32_16x16x32_bf16(a, b, acc[cg], 0, 0, 0);
            }
        }
        __syncthreads();
    }
#pragma unroll
    for (int cg = 0; cg < 4; ++cg) {
        int col = d0 + cg * 16 + lr;
        float bv = bias[col];
        int hh = col >> 6, cc = col & 63;
#pragma unroll
        for (int reg = 0; reg < 4; ++reg) {
            int rr = r0 + w * 16 + lg * 4 + reg;
            float val = acc[cg][reg] + bv;
            o[(size_t)rr * DIM + col] = val;
            bfo[((size_t)(hh * 512) + rr) * 64 + cc] = f2bf(val);
        }
    }
}

// cvec: c0/c511 dot tables from bf16 copies. z=0: q . rk[0/511] -> C0Q/C511Q; z=1: k . rq[0/511]
__global__ __launch_bounds__(256) void cvec(const short* __restrict__ qbf,
        const short* __restrict__ kbf, const short* __restrict__ rqbf,
        const short* __restrict__ rkbf, float* __restrict__ ws) {
    int cid = blockIdx.x;           // 0..2047
    int z = cid >> 10;
    int rem = cid & 1023;
    int bh = rem >> 5, rb = rem & 31;
    int t = threadIdx.x;
    int rr = t >> 2, p = t & 3;
    int n = rb * 64 + rr;
    int h = bh & 15;
    const short* X = (z ? kbf : qbf) + ((size_t)bh * 2048 + n) * 64 + p * 16;
    const short* T = (z ? rqbf : rkbf) + (size_t)h * 512 * 64 + p * 16;
    bf16x8 x0 = *reinterpret_cast<const bf16x8*>(X);
    bf16x8 x1 = *reinterpret_cast<const bf16x8*>(X + 8);
    bf16x8 a0 = *reinterpret_cast<const bf16x8*>(T);
    bf16x8 a1 = *reinterpret_cast<const bf16x8*>(T + 8);
    bf16x8 c0 = *reinterpret_cast<const bf16x8*>(T + 511 * 64);
    bf16x8 c1 = *reinterpret_cast<const bf16x8*>(T + 511 * 64 + 8);
    float d0 = 0.f, d1 = 0.f;
#pragma unroll
    for (int e = 0; e < 8; ++e) {
        float xa = bf2f(x0[e]), xb = bf2f(x1[e]);
        d0 += xa * bf2f(a0[e]) + xb * bf2f(a1[e]);
        d1 += xa * bf2f(c0[e]) + xb * bf2f(c1[e]);
    }
    d0 += __shfl_xor(d0, 1); d0 += __shfl_xor(d0, 2);
    d1 += __shfl_xor(d1, 1); d1 += __shfl_xor(d1, 2);
    if (p == 0) {
        int o = bh * S + n;
        if (!z) { ws[WS_C0Q + o] = d0; ws[WS_C511Q + o] = d1; }
        else    { ws[WS_C0K + o] = d0; ws[WS_C511K + o] = d1; }
    }
}

// Unified output kernel. Per panel: nt-major sweep (R8 ordering), flat runs merged into
// 64x512 superblocks (2KB-contiguous row spans). 373 blocks/panel, 64 panels = 23872.
__global__ __launch_bounds__(256) void outk(const short* __restrict__ qbf,
        const short* __restrict__ kbf, const short* __restrict__ rqbf,
        const short* __restrict__ rkbf, const float* __restrict__ ws,
        float* __restrict__ out) {
    __shared__ short Yt[128 * 68];   // [g][m] (band path only)

    int bid = blockIdx.x;
    int wid = (bid & 7) * 2984 + (bid >> 3);   // 23872 = 8*2984, bijective
    int panel = wid / 373, o = wid % 373;
    int PK = panel >> 5, bh = panel & 31, h = bh & 15;
    int t = threadIdx.x;
    float* obase = out + (PK ? OUT_PK : OUT_QP) + (size_t)bh * S * S;

    // locate within panel: for each nt, [nL left-superblocks][nB band][nR right-superblocks]
    int nt = 0, rem = o, nL = 0, nB = 0, jlo = 0;
    for (; nt < 32; ++nt) {
        jlo = nt > 8 ? nt - 8 : 0;
        nL = (jlo + 7) >> 3;          // ceil(jlo*64/512)
        nB = nt - jlo + 1;
        int nR = (38 - nt) >> 3;      // ceil((2048-(nt+1)*64)/512)
        int tot = nL + nB + nR;
        if (rem < tot) break;
        rem -= tot;
    }
    int n0 = nt * 64;

    if (rem < nL || rem >= nL + nB) {
        // ---- flat superblock: 64 rows x W cols (W<=512) ----
        int left, j0, W;
        if (rem < nL) { left = 1; j0 = rem * 512; W = jlo * 64 - j0; }
        else          { left = 0; int rr = rem - nL - nB; j0 = (nt + 1) * 64 + rr * 512; W = 2048 - j0; }
        if (W > 512) W = 512;
        const float* cv = ws + (PK ? (left ? WS_C0K : WS_C511K)
                                   : (left ? WS_C0Q : WS_C511Q)) + bh * S;
        int w2 = t >> 7;                 // 2 row-groups of 32 rows
        int c = (t & 127) * 4;           // 128 col-threads x 4 floats = 512 cols
        int active = c < W;
        if (PK) {
            f32x4 cvv = {0.f, 0.f, 0.f, 0.f};
            if (active) cvv = *reinterpret_cast<const f32x4*>(cv + j0 + c);
#pragma unroll
            for (int i = 0; i < 32; ++i) {
                int n = n0 + w2 * 32 + i;
                if (active)
                    __builtin_nontemporal_store(cvv,
                        reinterpret_cast<f32x4*>(obase + (size_t)n * S + j0 + c));
            }
        } else {
#pragma unroll
            for (int i = 0; i < 32; ++i) {
                int n = n0 + w2 * 32 + i;
                float vs = cv[n];
                f32x4 v = { vs, vs, vs, vs };
                if (active)
                    __builtin_nontemporal_store(v,
                        reinterpret_cast<f32x4*>(obase + (size_t)n * S + j0 + c));
            }
        }
        return;
    }

    // ---- band tile ----
    int jt = jlo + (rem - nL);
    int j0 = jt * 64;
    int rlo = 511 + j0 - (n0 + 63); rlo = rlo < 0 ? 0 : rlo;

    const short* xb = (PK ? kbf : qbf) + ((size_t)bh * 2048 + (PK ? j0 : n0)) * 64;
    const short* tbase = (PK ? rqbf : rkbf) + (size_t)h * 512 * 64;

    int lane = t & 63, w = t >> 6, lr = lane & 15, lg = lane >> 4;
    // Same (lr, lg) convention for A and B => HW k-permutation cancels (verified R2-R12).
    const short* arow = xb + (w * 16 + lr) * 64 + lg * 8;
    bf16x8 a0 = *reinterpret_cast<const bf16x8*>(arow);
    bf16x8 a1 = *reinterpret_cast<const bf16x8*>(arow + 32);

    bf16x8 b0s[8], b1s[8];
#pragma unroll
    for (int s = 0; s < 8; ++s) {
        int trow = rlo + s * 16 + lr;
        trow = trow > 511 ? 511 : trow;   // in-bounds; g>=nT never gathered
        const short* brow = tbase + trow * 64 + lg * 8;
        b0s[s] = *reinterpret_cast<const bf16x8*>(brow);
        b1s[s] = *reinterpret_cast<const bf16x8*>(brow + 32);
    }
#pragma unroll
    for (int s = 0; s < 8; ++s) {
        f32x4 acc = {0.f, 0.f, 0.f, 0.f};
        acc = __builtin_amdgcn_mfma_f32_16x16x32_bf16(a0, b0s[s], acc, 0, 0, 0);
        acc = __builtin_amdgcn_mfma_f32_16x16x32_bf16(a1, b1s[s], acc, 0, 0, 0);
        // lane's acc[reg] = Y[m = w*16+lg*4+reg, g = s*16+lr] -> ds_write_b64 at Yt[g][m0]
        short4 pk4 = { f2bf(acc[0]), f2bf(acc[1]), f2bf(acc[2]), f2bf(acc[3]) };
        *reinterpret_cast<short4*>(&Yt[(s * 16 + lr) * 68 + w * 16 + lg * 4]) = pk4;
    }
    __syncthreads();

    int tx = t & 15, ty = t >> 4;
#pragma unroll
    for (int i = 0; i < 4; ++i) {
        int rowi = ty + i * 16;
        int n = n0 + rowi;
        float vv[4];
#pragma unroll
        for (int jj = 0; jj < 4; ++jj) {
            int j = j0 + tx * 4 + jj;
            int rel = 511 + j - n;
            rel = rel < 0 ? 0 : (rel > 511 ? 511 : rel);
            int g = rel - rlo;
            int m = PK ? (tx * 4 + jj) : rowi;
            vv[jj] = bf2f(Yt[g * 68 + m]);
        }
        f32x4 v = { vv[0], vv[1], vv[2], vv[3] };
        __builtin_nontemporal_store(v,
            reinterpret_cast<f32x4*>(obase + (size_t)n * S + j0 + tx * 4));
    }
}

extern "C" void kernel_launch(void* const* d_in, const int* in_sizes, int n_in,
                              void* d_out, int out_size, void* d_ws, size_t ws_size,
                              hipStream_t stream) {
    const float* q    = (const float*)d_in[0];
    const float* k    = (const float*)d_in[1];
    const float* emb  = (const float*)d_in[2];
    const float* lnsc = (const float*)d_in[3];
    const float* lnbi = (const float*)d_in[4];
    const float* Wq   = (const float*)d_in[5];
    const float* bq   = (const float*)d_in[6];
    const float* Wk   = (const float*)d_in[7];
    const float* bk   = (const float*)d_in[8];
    float* out = (float*)d_out;
    float* ws  = (float*)d_ws;

    short* qbf  = (short*)(ws + WS_BF_BASE);
    short* kbf  = qbf + (size_t)4194304;
    short* rqbf = kbf + (size_t)4194304;
    short* rkbf = rqbf + (size_t)524288;

    prep1<<<dim3(2304), dim3(256), 0, stream>>>(emb, lnsc, lnbi, Wq, bq, Wk, bk,
                                                q, k, out, rqbf, rkbf, qbf, kbf);
    cvec<<<dim3(2048), dim3(256), 0, stream>>>(qbf, kbf, rqbf, rkbf, ws);
    outk<<<dim3(23872), dim3(256), 0, stream>>>(qbf, kbf, rqbf, rkbf, ws, out);
}